// Round 1
// baseline (838.882 us; speedup 1.0000x reference)
//
#include <hip/hip_runtime.h>

#define IN_CH 128
#define HIDDEN 64

// ---------------- CSR build ----------------

__global__ void count_kernel(const int* __restrict__ col, int* __restrict__ cnt, int E) {
    int i = blockIdx.x * blockDim.x + threadIdx.x;
    if (i < E) atomicAdd(&cnt[col[i]], 1);
}

__global__ __launch_bounds__(1024)
void scan1_kernel(const int* __restrict__ cnt, int* __restrict__ off,
                  int* __restrict__ bsum, int N) {
    __shared__ int s[1024];
    const int tid = threadIdx.x;
    const int i = blockIdx.x * 1024 + tid;
    int v = (i < N) ? cnt[i] : 0;
    s[tid] = v;
    __syncthreads();
    for (int d = 1; d < 1024; d <<= 1) {
        int t = (tid >= d) ? s[tid - d] : 0;
        __syncthreads();
        s[tid] += t;
        __syncthreads();
    }
    if (i < N) off[i] = s[tid] - v;              // exclusive within block
    if (tid == 1023) bsum[blockIdx.x] = s[1023]; // block total
}

__global__ void scan2_kernel(const int* __restrict__ bsum, int* __restrict__ boff, int nb) {
    if (blockIdx.x == 0 && threadIdx.x == 0) {
        int run = 0;
        for (int b = 0; b < nb; ++b) { boff[b] = run; run += bsum[b]; }
    }
}

__global__ void scan3_kernel(const int* __restrict__ cnt, int* __restrict__ off,
                             const int* __restrict__ boff, int* __restrict__ pos,
                             float* __restrict__ dinv, int N, int E) {
    int i = blockIdx.x * blockDim.x + threadIdx.x;
    if (i < N) {
        int o = off[i] + boff[i >> 10];
        off[i] = o;
        pos[i] = o;
        dinv[i] = rsqrtf((float)cnt[i] + 1.0f);  // deg = 1 (self-loop) + in-degree
    }
    if (i == N) off[N] = E;
}

__global__ void fill_kernel(const int* __restrict__ row, const int* __restrict__ col,
                            int* __restrict__ pos, int* __restrict__ srcrow, int E) {
    int i = blockIdx.x * blockDim.x + threadIdx.x;
    if (i < E) {
        int c = col[i];
        int p = atomicAdd(&pos[c], 1);
        srcrow[p] = row[i];
    }
}

// ---------------- tiled fp32 GEMM: H[N,64] = X[N,K] @ W[K,64] ----------------
// 256 threads, 64-row tile, full 64-col width, BK=16, 4x4 micro-tile/thread.

template <int K>
__global__ __launch_bounds__(256)
void gemm_kernel(const float* __restrict__ X, const float* __restrict__ W,
                 float* __restrict__ H, int N) {
    constexpr int BK = 16;
    __shared__ float xs[BK][64];  // transposed tile: xs[k][row]
    __shared__ float ws[BK][64];  // ws[k][col]
    const int tid  = threadIdx.x;
    const int row0 = blockIdx.x * 64;
    const int tx4  = (tid & 15) << 2;   // col base
    const int ty4  = (tid >> 4) << 2;   // row base
    // staging indices
    const int lrow = tid >> 2;          // 0..63
    const int kq   = (tid & 3) << 2;    // 0,4,8,12
    const int wk   = tid >> 4;          // 0..15
    const int wc   = (tid & 15) << 2;   // 0..60
    int grow = row0 + lrow;
    if (grow >= N) grow = N - 1;        // clamp (stores are guarded)

    float acc[4][4] = {};
    for (int k0 = 0; k0 < K; k0 += BK) {
        const float4 xv = *reinterpret_cast<const float4*>(&X[(size_t)grow * K + k0 + kq]);
        const float4 wv = *reinterpret_cast<const float4*>(&W[(size_t)(k0 + wk) * 64 + wc]);
        __syncthreads();
        xs[kq + 0][lrow] = xv.x;
        xs[kq + 1][lrow] = xv.y;
        xs[kq + 2][lrow] = xv.z;
        xs[kq + 3][lrow] = xv.w;
        *reinterpret_cast<float4*>(&ws[wk][wc]) = wv;
        __syncthreads();
#pragma unroll
        for (int k = 0; k < BK; ++k) {
            const float4 a = *reinterpret_cast<const float4*>(&xs[k][ty4]);
            const float4 b = *reinterpret_cast<const float4*>(&ws[k][tx4]);
            const float av[4] = {a.x, a.y, a.z, a.w};
            const float bv[4] = {b.x, b.y, b.z, b.w};
#pragma unroll
            for (int r = 0; r < 4; ++r)
#pragma unroll
                for (int c = 0; c < 4; ++c)
                    acc[r][c] = fmaf(av[r], bv[c], acc[r][c]);
        }
    }
#pragma unroll
    for (int r = 0; r < 4; ++r) {
        int n = row0 + ty4 + r;
        if (n < N) {
            float4 v = make_float4(acc[r][0], acc[r][1], acc[r][2], acc[r][3]);
            *reinterpret_cast<float4*>(&H[(size_t)n * 64 + tx4]) = v;
        }
    }
}

// ---------------- pull-style aggregation, fused self-term + bias (+ReLU) ----
// one wave per target node; lane = feature.

template <bool RELU>
__global__ __launch_bounds__(256)
void gather_kernel(const float* __restrict__ H, const float* __restrict__ dinv,
                   const int* __restrict__ off, const int* __restrict__ srcrow,
                   const float* __restrict__ bias, float* __restrict__ A, int N) {
    const int lane = threadIdx.x & 63;
    const int c = blockIdx.x * 4 + (threadIdx.x >> 6);
    if (c >= N) return;
    const int lo = off[c], hi = off[c + 1];
    float acc = 0.f;
    for (int j = lo; j < hi; ++j) {
        const int r = srcrow[j];
        acc = fmaf(H[(size_t)r * 64 + lane], dinv[r], acc);
    }
    const float dc = dinv[c];
    float o = dc * acc + H[(size_t)c * 64 + lane] * dc * dc + bias[lane];
    if (RELU) o = fmaxf(o, 0.f);
    A[(size_t)c * 64 + lane] = o;
}

// ---------------- mean-pool (batch is sorted) + final linear ----------------

__global__ __launch_bounds__(256)
void pool_kernel(const float* __restrict__ A, const int* __restrict__ batch,
                 float* __restrict__ pooled, int* __restrict__ gcnt, int N) {
    const int g = blockIdx.x >> 3;       // 8 blocks per graph
    const int stripe = blockIdx.x & 7;
    // lower_bound(batch, g) / lower_bound(batch, g+1)
    int lo = 0, hi = N;
    while (lo < hi) { int m = (lo + hi) >> 1; if (batch[m] < g) lo = m + 1; else hi = m; }
    const int beg = lo;
    lo = beg; hi = N;
    while (lo < hi) { int m = (lo + hi) >> 1; if (batch[m] < g + 1) lo = m + 1; else hi = m; }
    const int end = lo;

    const int lane = threadIdx.x & 63;
    const int wsid = stripe * 4 + (threadIdx.x >> 6);  // 0..31 wave-stripes per graph
    float acc = 0.f;
    for (int i = beg + wsid; i < end; i += 32)
        acc += A[(size_t)i * 64 + lane];
    atomicAdd(&pooled[g * 64 + lane], acc);
    if (stripe == 0 && threadIdx.x == 0) gcnt[g] = end - beg;
}

__global__ void final_kernel(const float* __restrict__ pooled, const int* __restrict__ gcnt,
                             const float* __restrict__ Wlin, const float* __restrict__ blin,
                             float* __restrict__ out) {
    const int t = threadIdx.x;  // 128 threads: (g, o)
    const int g = t >> 1, o = t & 1;
    const float c = (float)max(gcnt[g], 1);
    float acc = 0.f;
    for (int k = 0; k < 64; ++k)
        acc = fmaf(pooled[g * 64 + k], Wlin[k * 2 + o], acc);
    out[g * 2 + o] = acc / c + blin[o];
}

// ---------------- launch ----------------

extern "C" void kernel_launch(void* const* d_in, const int* in_sizes, int n_in,
                              void* d_out, int out_size, void* d_ws, size_t ws_size,
                              hipStream_t stream) {
    const float* x     = (const float*)d_in[0];
    const int*   ei    = (const int*)d_in[1];
    const int*   batch = (const int*)d_in[2];
    const float* W1    = (const float*)d_in[3];
    const float* b1    = (const float*)d_in[4];
    const float* W2    = (const float*)d_in[5];
    const float* b2    = (const float*)d_in[6];
    const float* W3    = (const float*)d_in[7];
    const float* b3    = (const float*)d_in[8];
    const float* Wlin  = (const float*)d_in[9];
    const float* blin  = (const float*)d_in[10];

    const int N = in_sizes[0] / IN_CH;
    const int E = in_sizes[1] / 2;
    const int* row = ei;
    const int* col = ei + E;

    char* p = (char*)d_ws;
    auto alloc = [&](size_t bytes) {
        char* q = p;
        p += (bytes + 511) & ~(size_t)511;
        return q;
    };
    int*   off    = (int*)alloc((size_t)(N + 1) * 4);
    int*   pos    = (int*)alloc((size_t)N * 4);
    int*   cnt    = (int*)alloc((size_t)N * 4);
    float* dinv   = (float*)alloc((size_t)N * 4);
    int*   srcrow = (int*)alloc((size_t)E * 4);
    float* Hbuf   = (float*)alloc((size_t)N * HIDDEN * 4);
    float* Abuf   = (float*)alloc((size_t)N * HIDDEN * 4);
    int*   bsum   = (int*)alloc(1024 * 4);
    int*   boff   = (int*)alloc(1024 * 4);
    float* pooled = (float*)alloc(64 * 64 * 4);
    int*   gcnt   = (int*)alloc(64 * 4);
    (void)ws_size; (void)n_in; (void)out_size;

    // --- CSR build (shared across the 3 conv layers) ---
    hipMemsetAsync(cnt, 0, (size_t)N * 4, stream);
    count_kernel<<<(E + 255) / 256, 256, 0, stream>>>(col, cnt, E);
    const int nb = (N + 1023) / 1024;
    scan1_kernel<<<nb, 1024, 0, stream>>>(cnt, off, bsum, N);
    scan2_kernel<<<1, 64, 0, stream>>>(bsum, boff, nb);
    scan3_kernel<<<(N + 1 + 255) / 256, 256, 0, stream>>>(cnt, off, boff, pos, dinv, N, E);
    fill_kernel<<<(E + 255) / 256, 256, 0, stream>>>(row, col, pos, srcrow, E);

    // --- 3 GCN layers ---
    const int gemm_grid   = (N + 63) / 64;
    const int gather_grid = (N + 3) / 4;
    gemm_kernel<IN_CH><<<gemm_grid, 256, 0, stream>>>(x, W1, Hbuf, N);
    gather_kernel<true><<<gather_grid, 256, 0, stream>>>(Hbuf, dinv, off, srcrow, b1, Abuf, N);
    gemm_kernel<HIDDEN><<<gemm_grid, 256, 0, stream>>>(Abuf, W2, Hbuf, N);
    gather_kernel<true><<<gather_grid, 256, 0, stream>>>(Hbuf, dinv, off, srcrow, b2, Abuf, N);
    gemm_kernel<HIDDEN><<<gemm_grid, 256, 0, stream>>>(Abuf, W3, Hbuf, N);
    gather_kernel<false><<<gather_grid, 256, 0, stream>>>(Hbuf, dinv, off, srcrow, b3, Abuf, N);

    // --- mean pool + final linear ---
    hipMemsetAsync(pooled, 0, 64 * 64 * 4, stream);
    pool_kernel<<<512, 256, 0, stream>>>(Abuf, batch, pooled, gcnt, N);
    final_kernel<<<1, 128, 0, stream>>>(pooled, gcnt, Wlin, blin, (float*)d_out);
}

// Round 2
// 562.993 us; speedup vs baseline: 1.4900x; 1.4900x over previous
//
#include <hip/hip_runtime.h>

#define IN_CH 128
#define HIDDEN 64

// ---------------- CSR build ----------------

__global__ void count_kernel(const int* __restrict__ col, int* __restrict__ cnt, int E) {
    int i = blockIdx.x * blockDim.x + threadIdx.x;
    if (i < E) atomicAdd(&cnt[col[i]], 1);
}

__global__ __launch_bounds__(1024)
void scan1_kernel(const int* __restrict__ cnt, int* __restrict__ off,
                  int* __restrict__ bsum, int N) {
    __shared__ int s[1024];
    const int tid = threadIdx.x;
    const int i = blockIdx.x * 1024 + tid;
    int v = (i < N) ? cnt[i] : 0;
    s[tid] = v;
    __syncthreads();
    for (int d = 1; d < 1024; d <<= 1) {
        int t = (tid >= d) ? s[tid - d] : 0;
        __syncthreads();
        s[tid] += t;
        __syncthreads();
    }
    if (i < N) off[i] = s[tid] - v;              // exclusive within block
    if (tid == 1023) bsum[blockIdx.x] = s[1023]; // block total
}

__global__ void scan2_kernel(const int* __restrict__ bsum, int* __restrict__ boff, int nb) {
    if (blockIdx.x == 0 && threadIdx.x == 0) {
        int run = 0;
        for (int b = 0; b < nb; ++b) { boff[b] = run; run += bsum[b]; }
    }
}

__global__ void scan3_kernel(const int* __restrict__ cnt, int* __restrict__ off,
                             const int* __restrict__ boff, int* __restrict__ pos,
                             float* __restrict__ dinv, int N, int E) {
    int i = blockIdx.x * blockDim.x + threadIdx.x;
    if (i < N) {
        int o = off[i] + boff[i >> 10];
        off[i] = o;
        pos[i] = o;
        dinv[i] = rsqrtf((float)cnt[i] + 1.0f);  // deg = 1 (self-loop) + in-degree
    }
    if (i == N) off[N] = E;
}

__global__ void fill_kernel(const int* __restrict__ row, const int* __restrict__ col,
                            int* __restrict__ pos, int* __restrict__ srcrow, int E) {
    int i = blockIdx.x * blockDim.x + threadIdx.x;
    if (i < E) {
        int c = col[i];
        int p = atomicAdd(&pos[c], 1);
        srcrow[p] = row[i];
    }
}

// ---------------- tiled fp32 GEMM: Hs[N,64] = (X[N,K] @ W[K,64]) * dinv[n] ---
// 256 threads, 64-row tile, full 64-col width, BK=16, 4x4 micro-tile/thread.
// dinv row-scaling folded into the epilogue so the gather loop needs no
// per-edge dinv load:  agg[c] = dinv[c] * (sum_r Hs[r] + Hs[c]).

template <int K>
__global__ __launch_bounds__(256)
void gemm_kernel(const float* __restrict__ X, const float* __restrict__ W,
                 const float* __restrict__ dinv, float* __restrict__ Hs, int N) {
    constexpr int BK = 16;
    __shared__ float xs[BK][64];  // transposed tile: xs[k][row]
    __shared__ float ws[BK][64];  // ws[k][col]
    const int tid  = threadIdx.x;
    const int row0 = blockIdx.x * 64;
    const int tx4  = (tid & 15) << 2;   // col base
    const int ty4  = (tid >> 4) << 2;   // row base
    // staging indices
    const int lrow = tid >> 2;          // 0..63
    const int kq   = (tid & 3) << 2;    // 0,4,8,12
    const int wk   = tid >> 4;          // 0..15
    const int wc   = (tid & 15) << 2;   // 0..60
    int grow = row0 + lrow;
    if (grow >= N) grow = N - 1;        // clamp (stores are guarded)

    float acc[4][4] = {};
    for (int k0 = 0; k0 < K; k0 += BK) {
        const float4 xv = *reinterpret_cast<const float4*>(&X[(size_t)grow * K + k0 + kq]);
        const float4 wv = *reinterpret_cast<const float4*>(&W[(size_t)(k0 + wk) * 64 + wc]);
        __syncthreads();
        xs[kq + 0][lrow] = xv.x;
        xs[kq + 1][lrow] = xv.y;
        xs[kq + 2][lrow] = xv.z;
        xs[kq + 3][lrow] = xv.w;
        *reinterpret_cast<float4*>(&ws[wk][wc]) = wv;
        __syncthreads();
#pragma unroll
        for (int k = 0; k < BK; ++k) {
            const float4 a = *reinterpret_cast<const float4*>(&xs[k][ty4]);
            const float4 b = *reinterpret_cast<const float4*>(&ws[k][tx4]);
            const float av[4] = {a.x, a.y, a.z, a.w};
            const float bv[4] = {b.x, b.y, b.z, b.w};
#pragma unroll
            for (int r = 0; r < 4; ++r)
#pragma unroll
                for (int c = 0; c < 4; ++c)
                    acc[r][c] = fmaf(av[r], bv[c], acc[r][c]);
        }
    }
#pragma unroll
    for (int r = 0; r < 4; ++r) {
        int n = row0 + ty4 + r;
        if (n < N) {
            const float dn = dinv[n];
            float4 v = make_float4(acc[r][0] * dn, acc[r][1] * dn,
                                   acc[r][2] * dn, acc[r][3] * dn);
            *reinterpret_cast<float4*>(&Hs[(size_t)n * 64 + tx4]) = v;
        }
    }
}

// ---------------- pull-style aggregation, fused self-term + bias (+ReLU) ----
// one wave per target node; lane = feature. Hs is pre-scaled by dinv[src],
// so the inner loop is a pure gather-sum; unrolled x8 for memory-level
// parallelism (8 independent 256B row loads in flight per wave).

template <bool RELU>
__global__ __launch_bounds__(256)
void gather_kernel(const float* __restrict__ Hs, const float* __restrict__ dinv,
                   const int* __restrict__ off, const int* __restrict__ srcrow,
                   const float* __restrict__ bias, float* __restrict__ A, int N) {
    const int lane = threadIdx.x & 63;
    const int c = blockIdx.x * 4 + (threadIdx.x >> 6);
    if (c >= N) return;
    const int lo = off[c], hi = off[c + 1];
    float acc = 0.f;
    int j = lo;
    for (; j + 8 <= hi; j += 8) {
        int r[8];
#pragma unroll
        for (int u = 0; u < 8; ++u) r[u] = srcrow[j + u];
        float h[8];
#pragma unroll
        for (int u = 0; u < 8; ++u) h[u] = Hs[(size_t)r[u] * 64 + lane];
#pragma unroll
        for (int u = 0; u < 8; ++u) acc += h[u];
    }
    if (j + 4 <= hi) {
        int r[4];
#pragma unroll
        for (int u = 0; u < 4; ++u) r[u] = srcrow[j + u];
        float h[4];
#pragma unroll
        for (int u = 0; u < 4; ++u) h[u] = Hs[(size_t)r[u] * 64 + lane];
#pragma unroll
        for (int u = 0; u < 4; ++u) acc += h[u];
        j += 4;
    }
    for (; j < hi; ++j)
        acc += Hs[(size_t)srcrow[j] * 64 + lane];

    const float dc = dinv[c];
    float o = dc * (acc + Hs[(size_t)c * 64 + lane]) + bias[lane];
    if (RELU) o = fmaxf(o, 0.f);
    A[(size_t)c * 64 + lane] = o;
}

// ---------------- mean-pool (batch is sorted) + final linear ----------------

__global__ __launch_bounds__(256)
void pool_kernel(const float* __restrict__ A, const int* __restrict__ batch,
                 float* __restrict__ pooled, int* __restrict__ gcnt, int N) {
    const int g = blockIdx.x >> 3;       // 8 blocks per graph
    const int stripe = blockIdx.x & 7;
    // lower_bound(batch, g) / lower_bound(batch, g+1)
    int lo = 0, hi = N;
    while (lo < hi) { int m = (lo + hi) >> 1; if (batch[m] < g) lo = m + 1; else hi = m; }
    const int beg = lo;
    lo = beg; hi = N;
    while (lo < hi) { int m = (lo + hi) >> 1; if (batch[m] < g + 1) lo = m + 1; else hi = m; }
    const int end = lo;

    const int lane = threadIdx.x & 63;
    const int wsid = stripe * 4 + (threadIdx.x >> 6);  // 0..31 wave-stripes per graph
    float acc = 0.f;
    for (int i = beg + wsid; i < end; i += 32)
        acc += A[(size_t)i * 64 + lane];
    atomicAdd(&pooled[g * 64 + lane], acc);
    if (stripe == 0 && threadIdx.x == 0) gcnt[g] = end - beg;
}

__global__ void final_kernel(const float* __restrict__ pooled, const int* __restrict__ gcnt,
                             const float* __restrict__ Wlin, const float* __restrict__ blin,
                             float* __restrict__ out) {
    const int t = threadIdx.x;  // 128 threads: (g, o)
    const int g = t >> 1, o = t & 1;
    const float c = (float)max(gcnt[g], 1);
    float acc = 0.f;
    for (int k = 0; k < 64; ++k)
        acc = fmaf(pooled[g * 64 + k], Wlin[k * 2 + o], acc);
    out[g * 2 + o] = acc / c + blin[o];
}

// ---------------- launch ----------------

extern "C" void kernel_launch(void* const* d_in, const int* in_sizes, int n_in,
                              void* d_out, int out_size, void* d_ws, size_t ws_size,
                              hipStream_t stream) {
    const float* x     = (const float*)d_in[0];
    const int*   ei    = (const int*)d_in[1];
    const int*   batch = (const int*)d_in[2];
    const float* W1    = (const float*)d_in[3];
    const float* b1    = (const float*)d_in[4];
    const float* W2    = (const float*)d_in[5];
    const float* b2    = (const float*)d_in[6];
    const float* W3    = (const float*)d_in[7];
    const float* b3    = (const float*)d_in[8];
    const float* Wlin  = (const float*)d_in[9];
    const float* blin  = (const float*)d_in[10];

    const int N = in_sizes[0] / IN_CH;
    const int E = in_sizes[1] / 2;
    const int* row = ei;
    const int* col = ei + E;

    char* p = (char*)d_ws;
    auto alloc = [&](size_t bytes) {
        char* q = p;
        p += (bytes + 511) & ~(size_t)511;
        return q;
    };
    int*   off    = (int*)alloc((size_t)(N + 1) * 4);
    int*   pos    = (int*)alloc((size_t)N * 4);
    int*   cnt    = (int*)alloc((size_t)N * 4);
    float* dinv   = (float*)alloc((size_t)N * 4);
    int*   srcrow = (int*)alloc((size_t)E * 4);
    float* Hbuf   = (float*)alloc((size_t)N * HIDDEN * 4);
    float* Abuf   = (float*)alloc((size_t)N * HIDDEN * 4);
    int*   bsum   = (int*)alloc(1024 * 4);
    int*   boff   = (int*)alloc(1024 * 4);
    float* pooled = (float*)alloc(64 * 64 * 4);
    int*   gcnt   = (int*)alloc(64 * 4);
    (void)ws_size; (void)n_in; (void)out_size;

    // --- CSR build (shared across the 3 conv layers; dinv needed by GEMM) ---
    hipMemsetAsync(cnt, 0, (size_t)N * 4, stream);
    count_kernel<<<(E + 255) / 256, 256, 0, stream>>>(col, cnt, E);
    const int nb = (N + 1023) / 1024;
    scan1_kernel<<<nb, 1024, 0, stream>>>(cnt, off, bsum, N);
    scan2_kernel<<<1, 64, 0, stream>>>(bsum, boff, nb);
    scan3_kernel<<<(N + 1 + 255) / 256, 256, 0, stream>>>(cnt, off, boff, pos, dinv, N, E);
    fill_kernel<<<(E + 255) / 256, 256, 0, stream>>>(row, col, pos, srcrow, E);

    // --- 3 GCN layers ---
    const int gemm_grid   = (N + 63) / 64;
    const int gather_grid = (N + 3) / 4;
    gemm_kernel<IN_CH><<<gemm_grid, 256, 0, stream>>>(x, W1, dinv, Hbuf, N);
    gather_kernel<true><<<gather_grid, 256, 0, stream>>>(Hbuf, dinv, off, srcrow, b1, Abuf, N);
    gemm_kernel<HIDDEN><<<gemm_grid, 256, 0, stream>>>(Abuf, W2, dinv, Hbuf, N);
    gather_kernel<true><<<gather_grid, 256, 0, stream>>>(Hbuf, dinv, off, srcrow, b2, Abuf, N);
    gemm_kernel<HIDDEN><<<gemm_grid, 256, 0, stream>>>(Abuf, W3, dinv, Hbuf, N);
    gather_kernel<false><<<gather_grid, 256, 0, stream>>>(Hbuf, dinv, off, srcrow, b3, Abuf, N);

    // --- mean pool + final linear ---
    hipMemsetAsync(pooled, 0, 64 * 64 * 4, stream);
    pool_kernel<<<512, 256, 0, stream>>>(Abuf, batch, pooled, gcnt, N);
    final_kernel<<<1, 128, 0, stream>>>(pooled, gcnt, Wlin, blin, (float*)d_out);
}

// Round 5
// 418.946 us; speedup vs baseline: 2.0024x; 1.3438x over previous
//
#include <hip/hip_runtime.h>

#define IN_CH 128
#define HIDDEN 64

// ================= CSR build: two-level LDS-binned counting sort ============
// bucket = col >> 8 (256-node ranges). Packed record (row<<8 | col&255) fits
// 32 bits since row < 2^17 for N=100k. Avoids the 16x write-amplification of
// a direct random 4B scatter (R2 profile: fill_kernel wrote 105MB for 6.4MB).

__global__ __launch_bounds__(512)
void bucket_hist_kernel(const int* __restrict__ col, int* __restrict__ bhist, int E) {
    __shared__ int h[512];
    h[threadIdx.x] = 0;
    __syncthreads();
    const int start = blockIdx.x * 8192;
    const int end = min(start + 8192, E);
    for (int e = start + threadIdx.x; e < end; e += 512)
        atomicAdd(&h[col[e] >> 8], 1);
    __syncthreads();
    if (h[threadIdx.x]) atomicAdd(&bhist[threadIdx.x], h[threadIdx.x]);
}

__global__ __launch_bounds__(512)
void bucket_scan_kernel(const int* __restrict__ bhist, int* __restrict__ bbase,
                        int* __restrict__ bpos, int* __restrict__ off,
                        int nb, int N, int E) {
    __shared__ int s[512];
    const int t = threadIdx.x;
    const int v = (t < nb) ? bhist[t] : 0;
    s[t] = v;
    __syncthreads();
    for (int d = 1; d < 512; d <<= 1) {
        int u = (t >= d) ? s[t - d] : 0;
        __syncthreads();
        s[t] += u;
        __syncthreads();
    }
    const int b = s[t] - v;   // exclusive
    if (t < nb) { bbase[t] = b; bpos[t] = b; }
    if (t == 0) { bbase[nb] = E; off[N] = E; }
}

__global__ __launch_bounds__(512)
void bucket_scatter_kernel(const int* __restrict__ row, const int* __restrict__ col,
                           int* __restrict__ bpos, unsigned* __restrict__ tmp, int E) {
    __shared__ int h[512];
    __shared__ int base[512];
    h[threadIdx.x] = 0;
    __syncthreads();
    const int start = blockIdx.x * 8192;
    const int end = min(start + 8192, E);
    for (int e = start + threadIdx.x; e < end; e += 512)
        atomicAdd(&h[col[e] >> 8], 1);
    __syncthreads();
    const int i = threadIdx.x;
    base[i] = h[i] ? atomicAdd(&bpos[i], h[i]) : 0;
    h[i] = 0;
    __syncthreads();
    for (int e = start + threadIdx.x; e < end; e += 512) {
        const int c = col[e];
        const int bk = c >> 8;
        const int p = base[bk] + atomicAdd(&h[bk], 1);
        tmp[p] = ((unsigned)row[e] << 8) | (unsigned)(c & 255);
    }
}

__global__ __launch_bounds__(256)
void bucket_sort_kernel(const unsigned* __restrict__ tmp, const int* __restrict__ bbase,
                        int* __restrict__ off, float* __restrict__ dinv,
                        int* __restrict__ srcrow, int N) {
    __shared__ int cnt[256];
    __shared__ int sc[256];
    const int b = blockIdx.x;
    const int node0 = b << 8;
    const int t = threadIdx.x;
    const int lo = bbase[b], hi = bbase[b + 1];
    cnt[t] = 0;
    __syncthreads();
    for (int j = lo + t; j < hi; j += 256)
        atomicAdd(&cnt[tmp[j] & 255u], 1);
    __syncthreads();
    const int v = cnt[t];
    sc[t] = v;
    __syncthreads();
    for (int d = 1; d < 256; d <<= 1) {
        int u = (t >= d) ? sc[t - d] : 0;
        __syncthreads();
        sc[t] += u;
        __syncthreads();
    }
    const int excl = sc[t] - v;
    const int node = node0 + t;
    if (node < N) {
        off[node] = lo + excl;
        dinv[node] = rsqrtf((float)v + 1.0f);   // deg = 1 (self-loop) + in-degree
    }
    cnt[t] = lo + excl;   // reuse as running write cursor
    __syncthreads();
    for (int j = lo + t; j < hi; j += 256) {
        const unsigned pk = tmp[j];
        const int p = atomicAdd(&cnt[pk & 255u], 1);
        srcrow[p] = (int)(pk >> 8);
    }
}

// ---------------- tiled fp32 GEMM: Hs[N,64] = (X[N,K] @ W[K,64]) * dinv[n] ---

template <int K>
__global__ __launch_bounds__(256)
void gemm_kernel(const float* __restrict__ X, const float* __restrict__ W,
                 const float* __restrict__ dinv, float* __restrict__ Hs, int N) {
    constexpr int BK = 16;
    __shared__ float xs[BK][64];
    __shared__ float ws[BK][64];
    const int tid  = threadIdx.x;
    const int row0 = blockIdx.x * 64;
    const int tx4  = (tid & 15) << 2;
    const int ty4  = (tid >> 4) << 2;
    const int lrow = tid >> 2;
    const int kq   = (tid & 3) << 2;
    const int wk   = tid >> 4;
    const int wc   = (tid & 15) << 2;
    int grow = row0 + lrow;
    if (grow >= N) grow = N - 1;

    float acc[4][4] = {};
    for (int k0 = 0; k0 < K; k0 += BK) {
        const float4 xv = *reinterpret_cast<const float4*>(&X[(size_t)grow * K + k0 + kq]);
        const float4 wv = *reinterpret_cast<const float4*>(&W[(size_t)(k0 + wk) * 64 + wc]);
        __syncthreads();
        xs[kq + 0][lrow] = xv.x;
        xs[kq + 1][lrow] = xv.y;
        xs[kq + 2][lrow] = xv.z;
        xs[kq + 3][lrow] = xv.w;
        *reinterpret_cast<float4*>(&ws[wk][wc]) = wv;
        __syncthreads();
#pragma unroll
        for (int k = 0; k < BK; ++k) {
            const float4 a = *reinterpret_cast<const float4*>(&xs[k][ty4]);
            const float4 b = *reinterpret_cast<const float4*>(&ws[k][tx4]);
            const float av[4] = {a.x, a.y, a.z, a.w};
            const float bv[4] = {b.x, b.y, b.z, b.w};
#pragma unroll
            for (int r = 0; r < 4; ++r)
#pragma unroll
                for (int c = 0; c < 4; ++c)
                    acc[r][c] = fmaf(av[r], bv[c], acc[r][c]);
        }
    }
#pragma unroll
    for (int r = 0; r < 4; ++r) {
        int n = row0 + ty4 + r;
        if (n < N) {
            const float dn = dinv[n];
            float4 v = make_float4(acc[r][0] * dn, acc[r][1] * dn,
                                   acc[r][2] * dn, acc[r][3] * dn);
            *reinterpret_cast<float4*>(&Hs[(size_t)n * 64 + tx4]) = v;
        }
    }
}

// ---------------- pull-style aggregation, fused self-term + bias (+ReLU) ----

template <bool RELU>
__global__ __launch_bounds__(256)
void gather_kernel(const float* __restrict__ Hs, const float* __restrict__ dinv,
                   const int* __restrict__ off, const int* __restrict__ srcrow,
                   const float* __restrict__ bias, float* __restrict__ A, int N) {
    const int lane = threadIdx.x & 63;
    const int c = blockIdx.x * 4 + (threadIdx.x >> 6);
    if (c >= N) return;
    const int lo = off[c], hi = off[c + 1];
    float acc = 0.f;
    int j = lo;
    for (; j + 8 <= hi; j += 8) {
        int r[8];
#pragma unroll
        for (int u = 0; u < 8; ++u) r[u] = srcrow[j + u];
        float h[8];
#pragma unroll
        for (int u = 0; u < 8; ++u) h[u] = Hs[(size_t)r[u] * 64 + lane];
#pragma unroll
        for (int u = 0; u < 8; ++u) acc += h[u];
    }
    if (j + 4 <= hi) {
        int r[4];
#pragma unroll
        for (int u = 0; u < 4; ++u) r[u] = srcrow[j + u];
        float h[4];
#pragma unroll
        for (int u = 0; u < 4; ++u) h[u] = Hs[(size_t)r[u] * 64 + lane];
#pragma unroll
        for (int u = 0; u < 4; ++u) acc += h[u];
        j += 4;
    }
    for (; j < hi; ++j)
        acc += Hs[(size_t)srcrow[j] * 64 + lane];

    const float dc = dinv[c];
    float o = dc * (acc + Hs[(size_t)c * 64 + lane]) + bias[lane];
    if (RELU) o = fmaxf(o, 0.f);
    A[(size_t)c * 64 + lane] = o;
}

// ---------------- mean-pool (batch is sorted) + final linear ----------------

__global__ __launch_bounds__(256)
void pool_kernel(const float* __restrict__ A, const int* __restrict__ batch,
                 float* __restrict__ pooled, int* __restrict__ gcnt, int N) {
    const int g = blockIdx.x >> 3;
    const int stripe = blockIdx.x & 7;
    int lo = 0, hi = N;
    while (lo < hi) { int m = (lo + hi) >> 1; if (batch[m] < g) lo = m + 1; else hi = m; }
    const int beg = lo;
    lo = beg; hi = N;
    while (lo < hi) { int m = (lo + hi) >> 1; if (batch[m] < g + 1) lo = m + 1; else hi = m; }
    const int end = lo;

    const int lane = threadIdx.x & 63;
    const int wsid = stripe * 4 + (threadIdx.x >> 6);
    float acc = 0.f;
    for (int i = beg + wsid; i < end; i += 32)
        acc += A[(size_t)i * 64 + lane];
    atomicAdd(&pooled[g * 64 + lane], acc);
    if (stripe == 0 && threadIdx.x == 0) gcnt[g] = end - beg;
}

__global__ void final_kernel(const float* __restrict__ pooled, const int* __restrict__ gcnt,
                             const float* __restrict__ Wlin, const float* __restrict__ blin,
                             float* __restrict__ out) {
    const int t = threadIdx.x;
    const int g = t >> 1, o = t & 1;
    const float c = (float)max(gcnt[g], 1);
    float acc = 0.f;
    for (int k = 0; k < 64; ++k)
        acc = fmaf(pooled[g * 64 + k], Wlin[k * 2 + o], acc);
    out[g * 2 + o] = acc / c + blin[o];
}

// ---------------- launch ----------------

extern "C" void kernel_launch(void* const* d_in, const int* in_sizes, int n_in,
                              void* d_out, int out_size, void* d_ws, size_t ws_size,
                              hipStream_t stream) {
    const float* x     = (const float*)d_in[0];
    const int*   ei    = (const int*)d_in[1];
    const int*   batch = (const int*)d_in[2];
    const float* W1    = (const float*)d_in[3];
    const float* b1    = (const float*)d_in[4];
    const float* W2    = (const float*)d_in[5];
    const float* b2    = (const float*)d_in[6];
    const float* W3    = (const float*)d_in[7];
    const float* b3    = (const float*)d_in[8];
    const float* Wlin  = (const float*)d_in[9];
    const float* blin  = (const float*)d_in[10];

    const int N = in_sizes[0] / IN_CH;
    const int E = in_sizes[1] / 2;
    const int* row = ei;
    const int* col = ei + E;
    const int nb = (N + 255) >> 8;   // coarse buckets (<=512)

    char* p = (char*)d_ws;
    auto alloc = [&](size_t bytes) {
        char* q = p;
        p += (bytes + 511) & ~(size_t)511;
        return q;
    };
    int*      off    = (int*)alloc((size_t)(N + 1) * 4);
    float*    dinv   = (float*)alloc((size_t)N * 4);
    int*      srcrow = (int*)alloc((size_t)E * 4);
    unsigned* tmp    = (unsigned*)alloc((size_t)E * 4);
    float*    Hbuf   = (float*)alloc((size_t)N * HIDDEN * 4);
    float*    Abuf   = (float*)alloc((size_t)N * HIDDEN * 4);
    int*      bhist  = (int*)alloc(512 * 4);
    int*      bbase  = (int*)alloc(513 * 4);
    int*      bpos   = (int*)alloc(512 * 4);
    float*    pooled = (float*)alloc(64 * 64 * 4);
    int*      gcnt   = (int*)alloc(64 * 4);
    (void)ws_size; (void)n_in; (void)out_size;

    // --- CSR build (bucket sort; also produces dinv for the GEMM epilogue) ---
    hipMemsetAsync(bhist, 0, 512 * 4, stream);
    const int eb = (E + 8191) / 8192;
    bucket_hist_kernel<<<eb, 512, 0, stream>>>(col, bhist, E);
    bucket_scan_kernel<<<1, 512, 0, stream>>>(bhist, bbase, bpos, off, nb, N, E);
    bucket_scatter_kernel<<<eb, 512, 0, stream>>>(row, col, bpos, tmp, E);
    bucket_sort_kernel<<<nb, 256, 0, stream>>>(tmp, bbase, off, dinv, srcrow, N);

    // --- 3 GCN layers ---
    const int gemm_grid   = (N + 63) / 64;
    const int gather_grid = (N + 3) / 4;
    gemm_kernel<IN_CH><<<gemm_grid, 256, 0, stream>>>(x, W1, dinv, Hbuf, N);
    gather_kernel<true><<<gather_grid, 256, 0, stream>>>(Hbuf, dinv, off, srcrow, b1, Abuf, N);
    gemm_kernel<HIDDEN><<<gemm_grid, 256, 0, stream>>>(Abuf, W2, dinv, Hbuf, N);
    gather_kernel<true><<<gather_grid, 256, 0, stream>>>(Hbuf, dinv, off, srcrow, b2, Abuf, N);
    gemm_kernel<HIDDEN><<<gemm_grid, 256, 0, stream>>>(Abuf, W3, dinv, Hbuf, N);
    gather_kernel<false><<<gather_grid, 256, 0, stream>>>(Hbuf, dinv, off, srcrow, b3, Abuf, N);

    // --- mean pool + final linear ---
    hipMemsetAsync(pooled, 0, 64 * 64 * 4, stream);
    pool_kernel<<<512, 256, 0, stream>>>(Abuf, batch, pooled, gcnt, N);
    final_kernel<<<1, 128, 0, stream>>>(pooled, gcnt, Wlin, blin, (float*)d_out);
}